// Round 1
// baseline (336.422 us; speedup 1.0000x reference)
//
#include <hip/hip_runtime.h>

typedef float f32x4 __attribute__((ext_vector_type(4)));

#define AX_X 0
#define AX_W1 1
#define AX_W2 2
#define AX_H 3
// scales: [0]=sx [1]=sw1 [2]=sw2 [3]=sx*sw1 [4]=sh [5]=sh*sw2

// ---------- exact e4m3fn RNE encode (matches ml_dtypes astype) ----------
__device__ __forceinline__ unsigned char fp8_encode(float t) {
  unsigned tb = __float_as_uint(t);
  unsigned sgn = (tb >> 24) & 0x80u;
  float a = fabsf(t);
  // subnormal path (|t| < 2^-6): round to multiple of 2^-9 (carry into normal ok)
  unsigned sb = (unsigned)(int)rintf(a * 512.0f);
  // normal path: RNE to 3 mantissa bits on the fp32 bit pattern
  unsigned u = tb & 0x7fffffffu;
  unsigned rem = u & 0xFFFFFu;
  unsigned keep = u & ~0xFFFFFu;
  unsigned inc = (rem > 0x80000u || (rem == 0x80000u && (keep & 0x100000u))) ? 0x100000u : 0u;
  keep += inc;
  int e = (int)(keep >> 23) - 127;            // [-6, 8] by construction (|t| <= ~448)
  unsigned nb = (unsigned)((e + 7) << 3) | ((keep >> 20) & 7u);
  unsigned b = (a < 0.015625f) ? sb : nb;
  return (unsigned char)(b | sgn);
}

__device__ __forceinline__ void gll16(const void* g, void* l) {
  __builtin_amdgcn_global_load_lds(
      (const __attribute__((address_space(1))) unsigned int*)g,
      (__attribute__((address_space(3))) unsigned int*)l, 16, 0, 0);
}

// ---------- init + amax ----------
__global__ __launch_bounds__(64, 1) void k_init(unsigned* amax) {
  if (threadIdx.x < 4) amax[threadIdx.x] = 0u;
}

__global__ __launch_bounds__(256, 4) void k_amax3(const float* __restrict__ x,
                                                  const float* __restrict__ w1,
                                                  const float* __restrict__ w2,
                                                  unsigned* __restrict__ amax) {
  int which = blockIdx.y;
  const float* p = which == 0 ? x : (which == 1 ? w1 : w2);
  int n4 = which == 0 ? (1048576 / 4) : (2097152 / 4);
  float m = 0.f;
  for (int i = blockIdx.x * 256 + threadIdx.x; i < n4; i += gridDim.x * 256) {
    float4 v = ((const float4*)p)[i];
    m = fmaxf(m, fmaxf(fmaxf(fabsf(v.x), fabsf(v.y)), fmaxf(fabsf(v.z), fabsf(v.w))));
  }
  for (int off = 32; off; off >>= 1) m = fmaxf(m, __shfl_xor(m, off));
  if ((threadIdx.x & 63) == 0) atomicMax(&amax[which], __float_as_uint(m));
}

__global__ void k_scales1(const unsigned* __restrict__ amax, float* __restrict__ scales) {
  float sx = fmaxf(__uint_as_float(amax[AX_X]) / 448.0f, 1e-12f);
  float s1 = fmaxf(__uint_as_float(amax[AX_W1]) / 448.0f, 1e-12f);
  float s2 = fmaxf(__uint_as_float(amax[AX_W2]) / 448.0f, 1e-12f);
  scales[0] = sx; scales[1] = s1; scales[2] = s2; scales[3] = sx * s1;
}

__global__ void k_scales2(const unsigned* __restrict__ amax, float* __restrict__ scales) {
  float sh = fmaxf(__uint_as_float(amax[AX_H]) / 448.0f, 1e-12f);
  scales[4] = sh; scales[5] = sh * scales[2];
}

// ---------- quantize x: [2048][512] fp32 -> fp8 bytes, same layout ----------
__global__ __launch_bounds__(256, 4) void k_quant_x(const float* __restrict__ x,
                                                    unsigned char* __restrict__ q,
                                                    const float* __restrict__ scales) {
  float s = scales[0];
  int i = blockIdx.x * 256 + threadIdx.x;  // 65536 threads, 16 elems each
  const float4* src = (const float4*)x + (size_t)i * 4;
  union { unsigned char b[16]; uint4 u; } o;
#pragma unroll
  for (int p = 0; p < 4; p++) {
    float4 v = src[p];
    o.b[p * 4 + 0] = fp8_encode(v.x / s);
    o.b[p * 4 + 1] = fp8_encode(v.y / s);
    o.b[p * 4 + 2] = fp8_encode(v.z / s);
    o.b[p * 4 + 3] = fp8_encode(v.w / s);
  }
  *(uint4*)(q + (size_t)i * 16) = o.u;
}

// ---------- quantize+transpose w1: [512][4096] -> qw1t [4096][512] fp8 ----------
__global__ __launch_bounds__(256, 2) void k_quant_w1t(const float* __restrict__ w1,
                                                      unsigned char* __restrict__ qt,
                                                      const float* __restrict__ scales) {
  __shared__ float tile[64 * 68];
  float s = scales[1];
  int n0 = blockIdx.x * 64, c0 = blockIdx.y * 64;
  int t = threadIdx.x;
  int row = t >> 2, q4 = t & 3;
  const float* src = w1 + (size_t)(c0 + row) * 4096 + n0 + q4 * 16;
#pragma unroll
  for (int p = 0; p < 4; p++) {
    float4 v = *(const float4*)(src + p * 4);
    *(float4*)&tile[row * 68 + q4 * 16 + p * 4] = v;
  }
  __syncthreads();
  int nl = t >> 2, ch = t & 3;
  union { unsigned char b[16]; uint4 u; } o;
#pragma unroll
  for (int j = 0; j < 16; j++) o.b[j] = fp8_encode(tile[(ch * 16 + j) * 68 + nl] / s);
  *(uint4*)(qt + (size_t)(n0 + nl) * 512 + c0 + ch * 16) = o.u;
}

// ---------- quantize+transpose [rows][32d*128e] fp32 -> [128e][rows][32d] fp8 ----------
__global__ __launch_bounds__(256, 2) void k_quant_de(const float* __restrict__ src,
                                                     unsigned char* __restrict__ dst,
                                                     const float* __restrict__ scales,
                                                     int sidx, int nrows) {
  __shared__ float tile[32 * 132];
  float s = scales[sidx];
  int row = blockIdx.x, t = threadIdx.x;
  const float* sp = src + (size_t)row * 4096;
#pragma unroll
  for (int p = 0; p < 4; p++) {
    int n = (p * 256 + t) * 4;
    float4 v = *(const float4*)(sp + n);
    *(float4*)&tile[(n >> 7) * 132 + (n & 127)] = v;
  }
  __syncthreads();
  int e = t >> 1, half = t & 1;
  union { unsigned char b[16]; uint4 u; } o;
#pragma unroll
  for (int j = 0; j < 16; j++) o.b[j] = fp8_encode(tile[(half * 16 + j) * 132 + e] / s);
  *(uint4*)(dst + ((size_t)e * nrows + row) * 32 + half * 16) = o.u;
}

// ---------- GEMM1: h[2048][4096] = (qx[2048][512] @ qw1t[4096][512]^T) * s1, fused amax ----------
__global__ __launch_bounds__(256, 2) void k_gemm1(const unsigned char* __restrict__ qa,
                                                  const unsigned char* __restrict__ qb,
                                                  float* __restrict__ h,
                                                  const float* __restrict__ scales,
                                                  unsigned* __restrict__ amax) {
  __shared__ unsigned char As[4096], Bs[4096];  // [128 rows][32 k-bytes]
  int m0 = blockIdx.y * 128, n0 = blockIdx.x * 128;
  int t = threadIdx.x, lane = t & 63, w = t >> 6, wr = w >> 1, wc = w & 1;
  f32x4 acc[4][4] = {};
  const unsigned char* ag = qa + (size_t)(m0 + (t >> 1)) * 512 + (t & 1) * 16;
  const unsigned char* bg = qb + (size_t)(n0 + (t >> 1)) * 512 + (t & 1) * 16;
  const int wbase = w * 1024;
  const int abase = (wr * 64 + (lane & 15)) * 32 + ((lane >> 4) << 3);
  const int bbase = (wc * 64 + (lane & 15)) * 32 + ((lane >> 4) << 3);

  for (int k0 = 0; k0 < 512; k0 += 32) {
    gll16(ag + k0, As + wbase);
    gll16(bg + k0, Bs + wbase);
    __syncthreads();  // drains vmcnt -> LDS tiles ready
    long a[4], b[4];
#pragma unroll
    for (int i = 0; i < 4; i++) {
      a[i] = *(const long*)(As + abase + i * 512);
      b[i] = *(const long*)(Bs + bbase + i * 512);
    }
#pragma unroll
    for (int mi = 0; mi < 4; mi++)
#pragma unroll
      for (int ni = 0; ni < 4; ni++)
        acc[mi][ni] = __builtin_amdgcn_mfma_f32_16x16x32_fp8_fp8(a[mi], b[ni], acc[mi][ni], 0, 0, 0);
    __syncthreads();  // all reads done before next stage overwrites
  }

  float s1 = scales[3];
  float lmax = 0.f;
#pragma unroll
  for (int mi = 0; mi < 4; mi++)
#pragma unroll
    for (int ni = 0; ni < 4; ni++)
#pragma unroll
      for (int r = 0; r < 4; r++) {
        float v = acc[mi][ni][r] * s1;
        h[(size_t)(m0 + wr * 64 + mi * 16 + ((lane >> 4) << 2) + r) * 4096 +
          (n0 + wc * 64 + ni * 16 + (lane & 15))] = v;
        lmax = fmaxf(lmax, fabsf(v));
      }
  for (int off = 32; off; off >>= 1) lmax = fmaxf(lmax, __shfl_xor(lmax, off));
  if (lane == 0) atomicMax(&amax[AX_H], __float_as_uint(lmax));
}

// ---------- GEMM2: out[m][c][e] = s2 * sum_d qh[e][m][d]*qw2[e][c][d] ----------
__global__ __launch_bounds__(256, 2) void k_gemm2(const unsigned char* __restrict__ qh,
                                                  const unsigned char* __restrict__ qw2,
                                                  const float* __restrict__ scales,
                                                  float* __restrict__ out) {
  int c0 = blockIdx.x * 16, m0 = blockIdx.y * 16;
  int t = threadIdx.x, lane = t & 63, w = t >> 6;
  int e0 = w * 32;
  const unsigned char* A = qh + ((size_t)e0 * 2048 + m0 + (lane & 15)) * 32 + ((lane >> 4) << 3);
  const unsigned char* B = qw2 + ((size_t)e0 * 512 + c0 + (lane & 15)) * 32 + ((lane >> 4) << 3);
  f32x4 acc[32];
#pragma unroll
  for (int e = 0; e < 32; e++) {
    long a = *(const long*)(A + (size_t)e * 2048 * 32);
    long b = *(const long*)(B + (size_t)e * 512 * 32);
    f32x4 z = {0.f, 0.f, 0.f, 0.f};
    acc[e] = __builtin_amdgcn_mfma_f32_16x16x32_fp8_fp8(a, b, z, 0, 0, 0);
  }
  float s2 = scales[5];
  int mr = m0 + ((lane >> 4) << 2);
  int cc = c0 + (lane & 15);
#pragma unroll
  for (int r = 0; r < 4; r++) {
    float* orow = out + ((size_t)(mr + r) * 512 + cc) * 128 + e0;
#pragma unroll
    for (int g = 0; g < 8; g++) {
      float4 v = make_float4(acc[g * 4 + 0][r] * s2, acc[g * 4 + 1][r] * s2,
                             acc[g * 4 + 2][r] * s2, acc[g * 4 + 3][r] * s2);
      *(float4*)(orow + g * 4) = v;
    }
  }
}

extern "C" void kernel_launch(void* const* d_in, const int* in_sizes, int n_in,
                              void* d_out, int out_size, void* d_ws, size_t ws_size,
                              hipStream_t stream) {
  const float* x  = (const float*)d_in[0];   // [4,512,512]  -> [2048][512]
  const float* w1 = (const float*)d_in[1];   // [512,32,128] -> [512][4096]
  const float* w2 = (const float*)d_in[2];   // [512,32,128] -> [512][4096]
  float* out = (float*)d_out;                // [2048][512][128]

  unsigned* amax = (unsigned*)d_ws;          // 4 slots
  float* scales = (float*)d_ws + 8;          // 6 slots
  unsigned char* base = (unsigned char*)d_ws + 256;
  unsigned char* qx   = base;                          // 1 MB  [2048][512]
  unsigned char* qw1t = qx   + (size_t)2048 * 512;     // 2 MB  [4096][512]
  unsigned char* qw2  = qw1t + (size_t)4096 * 512;     // 2 MB  [128][512][32]
  unsigned char* qh   = qw2  + (size_t)128 * 512 * 32; // 8 MB  [128][2048][32]
  float* h = (float*)(qh + (size_t)128 * 2048 * 32);   // 32 MB [2048][4096]

  k_init<<<dim3(1), dim3(64), 0, stream>>>(amax);
  k_amax3<<<dim3(64, 3), dim3(256), 0, stream>>>(x, w1, w2, amax);
  k_scales1<<<dim3(1), dim3(1), 0, stream>>>(amax, scales);
  k_quant_x<<<dim3(256), dim3(256), 0, stream>>>(x, qx, scales);
  k_quant_w1t<<<dim3(64, 8), dim3(256), 0, stream>>>(w1, qw1t, scales);
  k_quant_de<<<dim3(512), dim3(256), 0, stream>>>(w2, qw2, scales, 2, 512);
  k_gemm1<<<dim3(32, 16), dim3(256), 0, stream>>>(qx, qw1t, h, scales, amax);
  k_scales2<<<dim3(1), dim3(1), 0, stream>>>(amax, scales);
  k_quant_de<<<dim3(2048), dim3(256), 0, stream>>>(h, qh, scales, 4, 2048);
  k_gemm2<<<dim3(32, 128), dim3(256), 0, stream>>>(qh, qw2, scales, out);
}

// Round 2
// 214.349 us; speedup vs baseline: 1.5695x; 1.5695x over previous
//
#include <hip/hip_runtime.h>

typedef float f32x4 __attribute__((ext_vector_type(4)));

#define AX_X 0
#define AX_W1 1
#define AX_W2 2
#define AX_H 3

// ---------- exact e4m3fn RNE encode (matches ml_dtypes astype) ----------
__device__ __forceinline__ unsigned char fp8_encode(float t) {
  unsigned tb = __float_as_uint(t);
  unsigned sgn = (tb >> 24) & 0x80u;
  float a = fabsf(t);
  unsigned sb = (unsigned)(int)rintf(a * 512.0f);  // subnormal path (|t| < 2^-6)
  unsigned u = tb & 0x7fffffffu;
  unsigned rem = u & 0xFFFFFu;
  unsigned keep = u & ~0xFFFFFu;
  unsigned inc = (rem > 0x80000u || (rem == 0x80000u && (keep & 0x100000u))) ? 0x100000u : 0u;
  keep += inc;
  int e = (int)(keep >> 23) - 127;
  unsigned nb = (unsigned)((e + 7) << 3) | ((keep >> 20) & 7u);
  unsigned b = (a < 0.015625f) ? sb : nb;
  return (unsigned char)(b | sgn);
}

__device__ __forceinline__ float scale_of(const unsigned* amax, int i) {
  return fmaxf(__uint_as_float(amax[i]) / 448.0f, 1e-12f);
}

__device__ __forceinline__ void gll16(const void* g, void* l) {
  __builtin_amdgcn_global_load_lds(
      (const __attribute__((address_space(1))) unsigned int*)g,
      (__attribute__((address_space(3))) unsigned int*)l, 16, 0, 0);
}

// ---------- init + amax ----------
__global__ __launch_bounds__(64, 1) void k_init(unsigned* amax) {
  if (threadIdx.x < 4) amax[threadIdx.x] = 0u;
}

__global__ __launch_bounds__(256, 4) void k_amax3(const float* __restrict__ x,
                                                  const float* __restrict__ w1,
                                                  const float* __restrict__ w2,
                                                  unsigned* __restrict__ amax) {
  int which = blockIdx.y;
  const float* p = which == 0 ? x : (which == 1 ? w1 : w2);
  int n4 = which == 0 ? (1048576 / 4) : (2097152 / 4);
  float m = 0.f;
  for (int i = blockIdx.x * 256 + threadIdx.x; i < n4; i += gridDim.x * 256) {
    float4 v = ((const float4*)p)[i];
    m = fmaxf(m, fmaxf(fmaxf(fabsf(v.x), fabsf(v.y)), fmaxf(fabsf(v.z), fabsf(v.w))));
  }
  for (int off = 32; off; off >>= 1) m = fmaxf(m, __shfl_xor(m, off));
  if ((threadIdx.x & 63) == 0) atomicMax(&amax[which], __float_as_uint(m));
}

// ---------- quantize x: [2048][512] fp32 -> fp8 bytes, same layout ----------
__global__ __launch_bounds__(256, 4) void k_quant_x(const float* __restrict__ x,
                                                    unsigned char* __restrict__ q,
                                                    const unsigned* __restrict__ amax) {
  float s = scale_of(amax, AX_X);
  int i = blockIdx.x * 256 + threadIdx.x;
  const float4* src = (const float4*)x + (size_t)i * 4;
  union { unsigned char b[16]; uint4 u; } o;
#pragma unroll
  for (int p = 0; p < 4; p++) {
    float4 v = src[p];
    o.b[p * 4 + 0] = fp8_encode(v.x / s);
    o.b[p * 4 + 1] = fp8_encode(v.y / s);
    o.b[p * 4 + 2] = fp8_encode(v.z / s);
    o.b[p * 4 + 3] = fp8_encode(v.w / s);
  }
  *(uint4*)(q + (size_t)i * 16) = o.u;
}

// ---------- quantize+transpose w1: [512][4096] -> qw1t [4096][512] fp8 ----------
__global__ __launch_bounds__(256, 2) void k_quant_w1t(const float* __restrict__ w1,
                                                      unsigned char* __restrict__ qt,
                                                      const unsigned* __restrict__ amax) {
  __shared__ float tile[64 * 68];
  float s = scale_of(amax, AX_W1);
  int n0 = blockIdx.x * 64, c0 = blockIdx.y * 64;
  int t = threadIdx.x;
  int row = t >> 2, q4 = t & 3;
  const float* src = w1 + (size_t)(c0 + row) * 4096 + n0 + q4 * 16;
#pragma unroll
  for (int p = 0; p < 4; p++) {
    float4 v = *(const float4*)(src + p * 4);
    *(float4*)&tile[row * 68 + q4 * 16 + p * 4] = v;
  }
  __syncthreads();
  int nl = t >> 2, ch = t & 3;
  union { unsigned char b[16]; uint4 u; } o;
#pragma unroll
  for (int j = 0; j < 16; j++) o.b[j] = fp8_encode(tile[(ch * 16 + j) * 68 + nl] / s);
  *(uint4*)(qt + (size_t)(n0 + nl) * 512 + c0 + ch * 16) = o.u;
}

// ---------- quantize+transpose [rows][32d*128e] fp32 -> [128e][rows][32d] fp8 ----------
__global__ __launch_bounds__(256, 2) void k_quant_de(const float* __restrict__ src,
                                                     unsigned char* __restrict__ dst,
                                                     const unsigned* __restrict__ amax,
                                                     int aidx, int nrows) {
  __shared__ float tile[32 * 132];
  float s = scale_of(amax, aidx);
  int row = blockIdx.x, t = threadIdx.x;
  const float* sp = src + (size_t)row * 4096;
#pragma unroll
  for (int p = 0; p < 4; p++) {
    int n = (p * 256 + t) * 4;
    float4 v = *(const float4*)(sp + n);
    *(float4*)&tile[(n >> 7) * 132 + (n & 127)] = v;
  }
  __syncthreads();
  int e = t >> 1, half = t & 1;
  union { unsigned char b[16]; uint4 u; } o;
#pragma unroll
  for (int j = 0; j < 16; j++) o.b[j] = fp8_encode(tile[(half * 16 + j) * 132 + e] / s);
  *(uint4*)(dst + ((size_t)e * nrows + row) * 32 + half * 16) = o.u;
}

// ---------- GEMM1: h[2048][4096] = (qx @ qw1t^T) * sx*sw1, fused amax(h) ----------
__global__ __launch_bounds__(256, 2) void k_gemm1(const unsigned char* __restrict__ qa,
                                                  const unsigned char* __restrict__ qb,
                                                  float* __restrict__ h,
                                                  unsigned* __restrict__ amax) {
  __shared__ unsigned char As[4096], Bs[4096];  // [128 rows][32 k-bytes]
  int m0 = blockIdx.y * 128, n0 = blockIdx.x * 128;
  int t = threadIdx.x, lane = t & 63, w = t >> 6, wr = w >> 1, wc = w & 1;
  f32x4 acc[4][4] = {};
  const unsigned char* ag = qa + (size_t)(m0 + (t >> 1)) * 512 + (t & 1) * 16;
  const unsigned char* bg = qb + (size_t)(n0 + (t >> 1)) * 512 + (t & 1) * 16;
  const int wbase = w * 1024;
  const int abase = (wr * 64 + (lane & 15)) * 32 + ((lane >> 4) << 3);
  const int bbase = (wc * 64 + (lane & 15)) * 32 + ((lane >> 4) << 3);

  for (int k0 = 0; k0 < 512; k0 += 32) {
    gll16(ag + k0, As + wbase);
    gll16(bg + k0, Bs + wbase);
    __syncthreads();
    long a[4], b[4];
#pragma unroll
    for (int i = 0; i < 4; i++) {
      a[i] = *(const long*)(As + abase + i * 512);
      b[i] = *(const long*)(Bs + bbase + i * 512);
    }
#pragma unroll
    for (int mi = 0; mi < 4; mi++)
#pragma unroll
      for (int ni = 0; ni < 4; ni++)
        acc[mi][ni] = __builtin_amdgcn_mfma_f32_16x16x32_fp8_fp8(a[mi], b[ni], acc[mi][ni], 0, 0, 0);
    __syncthreads();
  }

  float s1 = scale_of(amax, AX_X) * scale_of(amax, AX_W1);
  float lmax = 0.f;
#pragma unroll
  for (int mi = 0; mi < 4; mi++)
#pragma unroll
    for (int ni = 0; ni < 4; ni++)
#pragma unroll
      for (int r = 0; r < 4; r++) {
        float v = acc[mi][ni][r] * s1;
        h[(size_t)(m0 + wr * 64 + mi * 16 + ((lane >> 4) << 2) + r) * 4096 +
          (n0 + wc * 64 + ni * 16 + (lane & 15))] = v;
        lmax = fmaxf(lmax, fabsf(v));
      }
  for (int off = 32; off; off >>= 1) lmax = fmaxf(lmax, __shfl_xor(lmax, off));
  if (lane == 0) atomicMax(&amax[AX_H], __float_as_uint(lmax));
}

// ---------- GEMM2: out[m][c][e] = s2 * sum_d qh[e][m][d]*qw2[e][c][d] ----------
// XCD-swizzled grid: each XCD owns 16 consecutive m-tiles -> qh slice L2-resident.
// Epilogue staged through per-wave LDS so each store instr writes 8 full 128B lines.
__global__ __launch_bounds__(256, 2) void k_gemm2(const unsigned char* __restrict__ qh,
                                                  const unsigned char* __restrict__ qw2,
                                                  const unsigned* __restrict__ amax,
                                                  float* __restrict__ out) {
  __shared__ float lbuf[4 * 64 * 34];
  int bid = blockIdx.x;
  int sw = (bid & 7) * 512 + (bid >> 3);          // bijective, 4096 % 8 == 0
  int m0 = (sw >> 5) * 16, c0 = (sw & 31) * 16;
  int t = threadIdx.x, lane = t & 63, w = t >> 6;
  int e0 = w * 32;
  const unsigned char* A = qh + ((size_t)e0 * 2048 + m0 + (lane & 15)) * 32 + ((lane >> 4) << 3);
  const unsigned char* B = qw2 + ((size_t)e0 * 512 + c0 + (lane & 15)) * 32 + ((lane >> 4) << 3);
  f32x4 acc[32];
#pragma unroll
  for (int e = 0; e < 32; e++) {
    long a = *(const long*)(A + (size_t)e * 2048 * 32);
    long b = *(const long*)(B + (size_t)e * 512 * 32);
    f32x4 z = {0.f, 0.f, 0.f, 0.f};
    acc[e] = __builtin_amdgcn_mfma_f32_16x16x32_fp8_fp8(a, b, z, 0, 0, 0);
  }
  float s2 = scale_of(amax, AX_H) * scale_of(amax, AX_W2);
  float* lw = lbuf + w * (64 * 34);
#pragma unroll
  for (int r = 0; r < 4; r++) {
    // stage: lane holds (m = m0+(lane>>4)*4+r, c = c0+(lane&15)), 32 e-values
#pragma unroll
    for (int g = 0; g < 8; g++) {
      float2 v0 = make_float2(acc[4 * g + 0][r] * s2, acc[4 * g + 1][r] * s2);
      float2 v1 = make_float2(acc[4 * g + 2][r] * s2, acc[4 * g + 3][r] * s2);
      *(float2*)&lw[lane * 34 + 4 * g] = v0;
      *(float2*)&lw[lane * 34 + 4 * g + 2] = v1;
    }
    // read back transposed: instr i covers 8 (m,c) pairs x full 128B e-run
#pragma unroll
    for (int i = 0; i < 8; i++) {
      int p = i * 8 + (lane >> 3);
      float2 u0 = *(const float2*)&lw[p * 34 + (lane & 7) * 4];
      float2 u1 = *(const float2*)&lw[p * 34 + (lane & 7) * 4 + 2];
      float* dst = out + ((size_t)(m0 + ((p >> 4) << 2) + r) * 512 + c0 + (p & 15)) * 128 +
                   e0 + (lane & 7) * 4;
      *(float4*)dst = make_float4(u0.x, u0.y, u1.x, u1.y);
    }
  }
}

extern "C" void kernel_launch(void* const* d_in, const int* in_sizes, int n_in,
                              void* d_out, int out_size, void* d_ws, size_t ws_size,
                              hipStream_t stream) {
  const float* x  = (const float*)d_in[0];   // [2048][512]
  const float* w1 = (const float*)d_in[1];   // [512][4096]
  const float* w2 = (const float*)d_in[2];   // [512][4096]
  float* out = (float*)d_out;                // [2048][512][128]

  unsigned* amax = (unsigned*)d_ws;
  unsigned char* base = (unsigned char*)d_ws + 256;
  unsigned char* qx   = base;                          // 1 MB  [2048][512]
  unsigned char* qw1t = qx   + (size_t)2048 * 512;     // 2 MB  [4096][512]
  unsigned char* qw2  = qw1t + (size_t)4096 * 512;     // 2 MB  [128][512][32]
  unsigned char* qh   = qw2  + (size_t)128 * 512 * 32; // 8 MB  [128][2048][32]
  float* h = (float*)(qh + (size_t)128 * 2048 * 32);   // 32 MB [2048][4096]

  k_init<<<dim3(1), dim3(64), 0, stream>>>(amax);
  k_amax3<<<dim3(64, 3), dim3(256), 0, stream>>>(x, w1, w2, amax);
  k_quant_x<<<dim3(256), dim3(256), 0, stream>>>(x, qx, amax);
  k_quant_w1t<<<dim3(64, 8), dim3(256), 0, stream>>>(w1, qw1t, amax);
  k_quant_de<<<dim3(512), dim3(256), 0, stream>>>(w2, qw2, amax, AX_W2, 512);
  k_gemm1<<<dim3(32, 16), dim3(256), 0, stream>>>(qx, qw1t, h, amax);
  k_quant_de<<<dim3(2048), dim3(256), 0, stream>>>(h, qh, amax, AX_H, 2048);
  k_gemm2<<<dim3(4096), dim3(256), 0, stream>>>(qh, qw2, amax, out);
}